// Round 6
// baseline (256.706 us; speedup 1.0000x reference)
//
#include <hip/hip_runtime.h>
#include <math.h>

#define N_SRC 16384
#define M_REF 16384
#define DEMB  256
#define KNN_K 16
#define CAP   96
#define NC    32
#define GB    4.25f
#define CH    0.265625f        // 8.5/32, exact in fp32
#define NCELLS (NC * NC * NC)

__device__ __forceinline__ int cell_of(float x) {
    int c = (int)floorf((x + GB) * (1.0f / CH));
    return min(max(c, 0), NC - 1);
}

// ---------------- K1: zero cell cursors + build W_sym ----------------
__global__ void __launch_bounds__(256) zero_wsym_kernel(int* __restrict__ cursor,
                                                        const float* __restrict__ W,
                                                        float* __restrict__ wsym) {
    int b = blockIdx.x, t = threadIdx.x;
    if (b < NCELLS / 256) {                 // 128 blocks zero the 32768 cursors
        cursor[b * 256 + t] = 0;
    } else {                                // 256 blocks build wsym
        int i = b - NCELLS / 256, j = t;
        float a = (j >= i) ? W[i * DEMB + j] : 0.f;
        float c = (i >= j) ? W[j * DEMB + i] : 0.f;
        wsym[i * DEMB + j] = a + c;
    }
}

// ---------------- K2: histogram of ref cells ----------------
__global__ void __launch_bounds__(256) hist_kernel(const float* __restrict__ rp,
                                                   int* __restrict__ cursor) {
    int i = blockIdx.x * 256 + threadIdx.x;
    int cx = cell_of(rp[i * 3 + 0]);
    int cy = cell_of(rp[i * 3 + 1]);
    int cz = cell_of(rp[i * 3 + 2]);
    atomicAdd(&cursor[(cz * NC + cy) * NC + cx], 1);
}

// ---------------- K3: exclusive scan -> cell_start[0..NCELLS]; cursor := start ----
__global__ void __launch_bounds__(1024) scan_kernel(int* __restrict__ cursor,
                                                    int* __restrict__ cell_start) {
    __shared__ int part[1024];
    int t = threadIdx.x;
    int loc[32]; int s = 0;
    #pragma unroll
    for (int i = 0; i < 32; ++i) { loc[i] = s; s += cursor[t * 32 + i]; }
    part[t] = s;
    __syncthreads();
    for (int off = 1; off < 1024; off <<= 1) {
        int add = (t >= off) ? part[t - off] : 0;
        __syncthreads();
        part[t] += add;
        __syncthreads();
    }
    int ex = part[t] - s;                   // exclusive chunk base
    #pragma unroll
    for (int i = 0; i < 32; ++i) {
        cell_start[t * 32 + i] = ex + loc[i];
        cursor[t * 32 + i]     = ex + loc[i];
    }
    if (t == 1023) cell_start[NCELLS] = part[1023];
}

// ---------------- K4: scatter refs into CSR order  +  q = src_feats @ W_sym ----------
__global__ void __launch_bounds__(256) scatter_q_kernel(const float* __restrict__ rp,
        int* __restrict__ cursor, float4* __restrict__ refp4s, int* __restrict__ ridx_s,
        const float* __restrict__ src_feats, const float* __restrict__ wsym,
        float* __restrict__ q) {
    __shared__ __align__(16) float sf[32][DEMB];
    int tid = threadIdx.x;
    if (blockIdx.x < 64) {
        int i = blockIdx.x * 256 + tid;
        float x = rp[i * 3 + 0], y = rp[i * 3 + 1], z = rp[i * 3 + 2];
        int c = (cell_of(z) * NC + cell_of(y)) * NC + cell_of(x);
        int pos = atomicAdd(&cursor[c], 1);
        refp4s[pos] = make_float4(x, y, z, fmaf(x, x, fmaf(y, y, z * z)));
        ridx_s[pos] = i;
    } else {
        int n0 = (blockIdx.x - 64) * 32;
        int c0 = tid & 63;
        int rg = tid >> 6;
        {
            int c = c0 * 4;
            #pragma unroll
            for (int rr = 0; rr < 8; ++rr) {
                int r = rr * 4 + rg;
                *(float4*)&sf[r][c] = *(const float4*)&src_feats[(size_t)(n0 + r) * DEMB + c];
            }
        }
        __syncthreads();

        float acc[8][4];
        #pragma unroll
        for (int rr = 0; rr < 8; ++rr)
            #pragma unroll
            for (int cc = 0; cc < 4; ++cc) acc[rr][cc] = 0.f;

        for (int c4 = 0; c4 < 64; ++c4) {
            float wv[4][4];
            #pragma unroll
            for (int j = 0; j < 4; ++j)
                #pragma unroll
                for (int cc = 0; cc < 4; ++cc)
                    wv[j][cc] = wsym[(size_t)(c4 * 4 + j) * DEMB + c0 + cc * 64];
            #pragma unroll
            for (int rr = 0; rr < 8; ++rr) {
                float4 s4 = *(const float4*)&sf[rg * 8 + rr][c4 * 4];
                #pragma unroll
                for (int cc = 0; cc < 4; ++cc) {
                    float a = acc[rr][cc];
                    a = fmaf(s4.x, wv[0][cc], a);
                    a = fmaf(s4.y, wv[1][cc], a);
                    a = fmaf(s4.z, wv[2][cc], a);
                    a = fmaf(s4.w, wv[3][cc], a);
                    acc[rr][cc] = a;
                }
            }
        }
        #pragma unroll
        for (int rr = 0; rr < 8; ++rr)
            #pragma unroll
            for (int cc = 0; cc < 4; ++cc)
                q[(size_t)(n0 + rg * 8 + rr) * DEMB + (c0 + cc * 64)] = acc[rr][cc];
    }
}

// ---------------- bitonic sort of (d2, idx) pairs across 64 lanes ----------------
__device__ __forceinline__ void sort64_kv(float& vd, int& vi, int lane) {
    #pragma unroll
    for (int k = 2; k <= 64; k <<= 1) {
        #pragma unroll
        for (int j = k >> 1; j > 0; j >>= 1) {
            float od = __shfl_xor(vd, j, 64);
            int   oi = __shfl_xor(vi, j, 64);
            bool keep_min = (((lane & j) == 0) == ((lane & k) == 0));
            bool oless = (od < vd) || (od == vd && oi < vi);
            bool take = (keep_min == oless);
            vd = take ? od : vd;
            vi = take ? oi : vi;
        }
    }
}

// ---------------- K5: grid-accelerated exact KNN, one wave per src ----------------
// Cube r ∈ {1,2,4,...}: stream cube rows (x-contiguous CSR ranges).
// Phase 1: per-lane min (round-robin over the cube stream) -> bitonic -> tau =
//   16th-smallest lane-min (16 distinct real distances => sound bound on cube d16).
// Phase 2: gated LDS append; exact (d2,idx)-lex bitonic top-16.
// Stop when d16_true <= (r*h)^2*0.998 (unexamined points are > r*h away; clamped
// outliers are geometrically farther than their cell => bound still valid).
__global__ void __launch_bounds__(256) knn_kernel(const float* __restrict__ src_points,
        const float4* __restrict__ refp4s, const int* __restrict__ ridx_s,
        const int* __restrict__ cell_start,
        float* __restrict__ kd2, int* __restrict__ kidx) {
    const float INF = 3.0e38f;
    int tid = threadIdx.x;
    int wave = tid >> 6, lane = tid & 63;
    int n = blockIdx.x * 4 + wave;

    __shared__ float cd[4][CAP];
    __shared__ int   ci[4][CAP];
    __shared__ int   cnt[4];

    float sx = src_points[n * 3 + 0];
    float sy = src_points[n * 3 + 1];
    float sz = src_points[n * 3 + 2];
    float m2x = -2.f * sx, m2y = -2.f * sy, m2z = -2.f * sz;
    float sn2 = fmaf(sx, sx, fmaf(sy, sy, sz * sz));
    int cx = cell_of(sx), cy = cell_of(sy), cz = cell_of(sz);

    int r = (sn2 > 9.f) ? NC : 1;   // far-tail srcs go straight to full scan

    while (true) {
        int x0 = max(cx - r, 0), x1 = min(cx + r, NC - 1);
        int y0 = max(cy - r, 0), y1 = min(cy + r, NC - 1);
        int z0 = max(cz - r, 0), z1 = min(cz + r, NC - 1);
        bool full = (x0 == 0 && y0 == 0 && z0 == 0 &&
                     x1 == NC - 1 && y1 == NC - 1 && z1 == NC - 1);

        if (lane == 0) cnt[wave] = 0;

        // ---- phase 1 ----
        float mind = INF;
        if (full) {
            for (int p = lane; p < M_REF; p += 64) {
                float4 rp = refp4s[p];
                float d = fmaf(rp.x, m2x, rp.w);
                d = fmaf(rp.y, m2y, d);
                d = fmaf(rp.z, m2z, d);
                mind = fminf(mind, d);
            }
        } else {
            int off = 0;
            for (int zc = z0; zc <= z1; ++zc)
                for (int yc = y0; yc <= y1; ++yc) {
                    int rb = (zc * NC + yc) * NC;
                    int st = cell_start[rb + x0];
                    int en = cell_start[rb + x1 + 1];
                    int np = en - st;
                    for (int k = (lane - off) & 63; k < np; k += 64) {
                        float4 rp = refp4s[st + k];
                        float d = fmaf(rp.x, m2x, rp.w);
                        d = fmaf(rp.y, m2y, d);
                        d = fmaf(rp.z, m2z, d);
                        mind = fminf(mind, d);
                    }
                    off = (off + np) & 63;
                }
        }
        // bitonic sort of lane minima; tau = 16th smallest
        float v = mind;
        #pragma unroll
        for (int k = 2; k <= 64; k <<= 1) {
            #pragma unroll
            for (int j = k >> 1; j > 0; j >>= 1) {
                float o = __shfl_xor(v, j, 64);
                bool lower = (lane & j) == 0;
                bool up = (lane & k) == 0;
                float mn = fminf(v, o), mx = fmaxf(v, o);
                v = (lower == up) ? mn : mx;
            }
        }
        float tau = __shfl(v, 15, 64);

        // ---- phase 2: gated append ----
        if (full) {
            for (int p = lane; p < M_REF; p += 64) {
                float4 rp = refp4s[p];
                float d = fmaf(rp.x, m2x, rp.w);
                d = fmaf(rp.y, m2y, d);
                d = fmaf(rp.z, m2z, d);
                if (d <= tau) {
                    int pp = atomicAdd(&cnt[wave], 1);
                    if (pp < CAP) { cd[wave][pp] = d; ci[wave][pp] = ridx_s[p]; }
                }
            }
        } else {
            for (int zc = z0; zc <= z1; ++zc)
                for (int yc = y0; yc <= y1; ++yc) {
                    int rb = (zc * NC + yc) * NC;
                    int st = cell_start[rb + x0];
                    int en = cell_start[rb + x1 + 1];
                    int np = en - st;
                    for (int k = lane; k < np; k += 64) {
                        float4 rp = refp4s[st + k];
                        float d = fmaf(rp.x, m2x, rp.w);
                        d = fmaf(rp.y, m2y, d);
                        d = fmaf(rp.z, m2z, d);
                        if (d <= tau) {
                            int pp = atomicAdd(&cnt[wave], 1);
                            if (pp < CAP) { cd[wave][pp] = d; ci[wave][pp] = ridx_s[st + k]; }
                        }
                    }
                }
        }

        // ---- selection (per-wave; same-wave LDS ops are ordered) ----
        int count = cnt[wave];
        if (count > CAP) count = CAP;
        float vd = (lane < count) ? cd[wave][lane] : INF;
        int   vi = (lane < count) ? ci[wave][lane] : 0x7fffffff;
        sort64_kv(vd, vi, lane);
        int done = 64;
        while (done < count) {
            if (lane >= 16) {
                int p = done + (lane - 16);
                vd = (p < count) ? cd[wave][p] : INF;
                vi = (p < count) ? ci[wave][p] : 0x7fffffff;
            }
            sort64_kv(vd, vi, lane);
            done += 48;
        }
        float d16 = __shfl(vd, 15, 64) + sn2;
        float rb = (float)r * CH;
        if (full || d16 <= rb * rb * 0.998f) {
            if (lane < KNN_K) {
                kd2[(size_t)n * KNN_K + lane] = vd + sn2;
                kidx[(size_t)n * KNN_K + lane] = vi;
            }
            break;
        }
        r <<= 1;
        if (r > NC) r = NC;
    }
}

// ---------------- K6: scores, softmax, corres, w ----------------
__global__ void __launch_bounds__(256) score_kernel(const float* __restrict__ q,
                                                    const float* __restrict__ ref_feats,
                                                    const float* __restrict__ ref_points,
                                                    const float* __restrict__ src_points,
                                                    const float* __restrict__ kd2,
                                                    const int* __restrict__ kidx,
                                                    float* __restrict__ out) {
    int wave = threadIdx.x >> 6;
    int lane = threadIdx.x & 63;
    int n = __builtin_amdgcn_readfirstlane(blockIdx.x * 4 + wave);

    float4 qv = *(const float4*)&q[(size_t)n * DEMB + lane * 4];

    int idx[KNN_K]; float d2[KNN_K];
    #pragma unroll
    for (int k = 0; k < KNN_K; ++k) {
        idx[k] = __builtin_amdgcn_readfirstlane(kidx[(size_t)n * KNN_K + k]);
        d2[k]  = kd2[(size_t)n * KNN_K + k];
    }

    float sc[KNN_K];
    #pragma unroll
    for (int k = 0; k < KNN_K; ++k) {
        float4 r = *(const float4*)&ref_feats[(size_t)idx[k] * DEMB + lane * 4];
        float p = fmaf(r.x, qv.x, fmaf(r.y, qv.y, fmaf(r.z, qv.z, r.w * qv.w)));
        #pragma unroll
        for (int off = 1; off < 64; off <<= 1) p += __shfl_xor(p, off, 64);
        sc[k] = p;
    }

    float tv[KNN_K];
    #pragma unroll
    for (int k = 0; k < KNN_K; ++k) {
        float wt = fmaxf(0.f, fmaf(-2.f, d2[k], 1.f));
        tv[k] = sc[k] * wt;
    }
    float m = tv[0];
    #pragma unroll
    for (int k = 1; k < KNN_K; ++k) m = fmaxf(m, tv[k]);
    float e[KNN_K], s = 0.f;
    #pragma unroll
    for (int k = 0; k < KNN_K; ++k) { e[k] = expf(tv[k] - m); s += e[k]; }

    float cx = 0.f, cy = 0.f, cz = 0.f;
    #pragma unroll
    for (int k = 0; k < KNN_K; ++k) {
        float rx = ref_points[idx[k] * 3 + 0];
        float ry = ref_points[idx[k] * 3 + 1];
        float rz = ref_points[idx[k] * 3 + 2];
        cx = fmaf(e[k], rx, cx);
        cy = fmaf(e[k], ry, cy);
        cz = fmaf(e[k], rz, cz);
    }
    float inv = 1.f / s;
    cx *= inv; cy *= inv; cz *= inv;

    if (lane == 0) {
        float ssx = src_points[n * 3 + 0];
        float ssy = src_points[n * 3 + 1];
        float ssz = src_points[n * 3 + 2];
        float dx = ssx - cx, dy = ssy - cy, dz = ssz - cz;
        float dist = sqrtf(fmaf(dx, dx, fmaf(dy, dy, dz * dz)));
        float w = fmaxf(0.f, fmaf(-2.f, dist, 1.f));
        out[(size_t)n * 3 + 0] = cx;
        out[(size_t)n * 3 + 1] = cy;
        out[(size_t)n * 3 + 2] = cz;
        out[(size_t)N_SRC * 3 + n] = w;
    }
}

extern "C" void kernel_launch(void* const* d_in, const int* in_sizes, int n_in,
                              void* d_out, int out_size, void* d_ws, size_t ws_size,
                              hipStream_t stream) {
    const float* ref_points = (const float*)d_in[0];
    const float* src_points = (const float*)d_in[1];
    const float* ref_feats  = (const float*)d_in[2];
    const float* src_feats  = (const float*)d_in[3];
    const float* W          = (const float*)d_in[4];
    float* out = (float*)d_out;

    char* ws = (char*)d_ws;
    float4* refp4s     = (float4*)ws;                 ws += (size_t)M_REF * 16;
    float*  q          = (float*)ws;                  ws += (size_t)N_SRC * DEMB * 4;
    float*  wsym       = (float*)ws;                  ws += (size_t)DEMB * DEMB * 4;
    float*  kd2        = (float*)ws;                  ws += (size_t)N_SRC * KNN_K * 4;
    int*    kidx       = (int*)ws;                    ws += (size_t)N_SRC * KNN_K * 4;
    int*    ridx_s     = (int*)ws;                    ws += (size_t)M_REF * 4;
    int*    cell_start = (int*)ws;                    ws += (size_t)(NCELLS + 4) * 4;
    int*    cursor     = (int*)ws;

    zero_wsym_kernel<<<NCELLS / 256 + DEMB, 256, 0, stream>>>(cursor, W, wsym);
    hist_kernel<<<M_REF / 256, 256, 0, stream>>>(ref_points, cursor);
    scan_kernel<<<1, 1024, 0, stream>>>(cursor, cell_start);
    scatter_q_kernel<<<64 + N_SRC / 32, 256, 0, stream>>>(ref_points, cursor, refp4s, ridx_s,
                                                          src_feats, wsym, q);
    knn_kernel<<<N_SRC / 4, 256, 0, stream>>>(src_points, refp4s, ridx_s, cell_start, kd2, kidx);
    score_kernel<<<N_SRC / 4, 256, 0, stream>>>(q, ref_feats, ref_points, src_points, kd2, kidx, out);
}